// Round 5
// baseline (155.170 us; speedup 1.0000x reference)
//
#include <hip/hip_runtime.h>
#include <hip/hip_fp16.h>

// fePAM: per-pixel gather attention. Shapes fixed by setup_inputs().
constexpr int B = 2, C = 64, H = 128, W = 256, N = H * W, K = 32;

typedef _Float16 hf2 __attribute__((ext_vector_type(2)));

// DPP helper (VALU-pipe cross-lane)
template <int CTRL>
__device__ __forceinline__ float dppf(float x) {
    int i = __builtin_bit_cast(int, x);
    int r = __builtin_amdgcn_update_dpp(i, i, CTRL, 0xF, 0xF, false);
    return __builtin_bit_cast(float, r);
}
// ctrl: 0xB1 quad_perm xor1 | 0x4E quad_perm xor2 | 0x141 row_half_mirror
// (==xor4 after xor1/xor2 uniformity) | 0x128 row_ror:8 (==xor8 within 16)

// ---------------------------------------------------------------------------
// Prep: z=0/1/2 transpose+fp16 S,R,Q: [B][C][N] -> [B][N][C].
// z=3 (b==0 only): pack idx16[n][slot] = px*W+py, slot=(k&7)*4+(k>>3) so the
// attention lane (k_loc=lane>>3) reads its 4 g-indices as one 8B load.
// grid = (N/64, B, 4), block = 256.
// ---------------------------------------------------------------------------
__global__ __launch_bounds__(256) void fepam_prep(
    const float* __restrict__ Q, const float* __restrict__ S,
    const float* __restrict__ R,
    const int* __restrict__ Px, const int* __restrict__ Py,
    __half* __restrict__ Qt, __half* __restrict__ St, __half* __restrict__ Rt,
    unsigned short* __restrict__ Idx) {
    const int n0 = blockIdx.x * 64;
    const int b  = blockIdx.y;
    const int z  = blockIdx.z;

    if (z == 3) {
        if (b) return;
#pragma unroll
        for (int t = 0; t < 8; ++t) {
            const int e  = threadIdx.x + 256 * t;   // 0..2047
            const int nl = e >> 5, k = e & 31;
            const int n  = n0 + nl;
            const int idx = Px[(size_t)n * K + k] * W + Py[(size_t)n * K + k];
            Idx[(size_t)n * K + (k & 7) * 4 + (k >> 3)] = (unsigned short)idx;
        }
        return;
    }

    __shared__ float tile[C][65];
    const float* src = (z == 0 ? S : (z == 1 ? R : Q)) + (size_t)b * C * N;
    __half2* d2 = (__half2*)((z == 0 ? St : (z == 1 ? Rt : Qt)) +
                             (size_t)b * N * C);
    {
        const int j = threadIdx.x & 63, c0 = threadIdx.x >> 6;
        const float* s = src + n0 + j;
#pragma unroll
        for (int r = 0; r < 16; ++r) {
            int c = c0 + r * 4;
            tile[c][j] = s[(size_t)c * N];  // coalesced 256B along n
        }
    }
    __syncthreads();
    {
        const int c2 = threadIdx.x & 31, j0 = threadIdx.x >> 5;
#pragma unroll
        for (int r = 0; r < 8; ++r) {
            int j = j0 + 8 * r;
            d2[(size_t)(n0 + j) * 32 + c2] =
                __floats2half2_rn(tile[2 * c2][j], tile[2 * c2 + 1][j]);
        }
    }
}

// ---------------------------------------------------------------------------
// Attention. grid = (N/64 * B), block = 512 (8 waves; 1 wave = 8 pixels).
// Lane layout everywhere: c_oct = lane&7 (16B chunk of the 128B vector),
// k_loc = lane>>3 (key within octet); g = 0..3 indexes key octets (k=8g+k_loc).
// All gathers are 8 lanes x 16B contiguous per key/value vector.
// ---------------------------------------------------------------------------
__global__ __launch_bounds__(512, 8) void fepam_attn(
    const __half* __restrict__ Qt, const unsigned short* __restrict__ Idx,
    const __half* __restrict__ St, const __half* __restrict__ Rt,
    float* __restrict__ Out) {
    __shared__ __align__(16) float ot[64][66];  // 16.9 KB

    const int tid  = threadIdx.x;
    const int lane = tid & 63;
    const int wave = tid >> 6;
    const int bx   = blockIdx.x;
    const int b    = bx & 1;          // XCD batch-parity swizzle
    const int n0   = (bx >> 1) * 64;

    const int c_oct = lane & 7;
    const int k_loc = lane >> 3;
    const bool hi8  = (lane & 8)  != 0;
    const bool hi16 = (lane & 16) != 0;
    const bool hi32 = (lane & 32) != 0;

    const __half* Qtb = Qt + (size_t)b * N * C;
    const __half* Stb = St + (size_t)b * N * C;
    const __half* Rtb = Rt + (size_t)b * N * C;

#pragma unroll 2
    for (int p = 0; p < 8; ++p) {
        const int j = wave * 8 + p;
        const int n = n0 + j;

        // q fragment: 16B (8 halves) this lane needs — one 128B line per pixel
        const float4 qraw = *(const float4*)(Qtb + (size_t)n * C + c_oct * 8);
        // packed candidate indices for this lane's k_loc: 4 x uint16 (8B)
        const ushort4 iv = *(const ushort4*)(Idx + (size_t)n * K + k_loc * 4);
        const int idxg[4] = {iv.x, iv.y, iv.z, iv.w};

        // ---- phase 1: per-lane key-chunk dots (contiguous 128B per key)
        float s[4];
#pragma unroll
        for (int g = 0; g < 4; ++g) {
            const float4 kraw =
                *(const float4*)(Stb + ((size_t)idxg[g] << 6) + c_oct * 8);
            const hf2* k2 = (const hf2*)&kraw;
            const hf2* q2 = (const hf2*)&qraw;
            float acc = 0.f;
#pragma unroll
            for (int u = 0; u < 4; ++u)
                acc = __builtin_amdgcn_fdot2(k2[u], q2[u], acc, false);
            s[g] = acc;
        }
        // reduce each s[g] over c_oct (lanes 0..7 of the group): pure DPP
#pragma unroll
        for (int g = 0; g < 4; ++g) {
            s[g] += dppf<0xB1>(s[g]);
            s[g] += dppf<0x4E>(s[g]);
            s[g] += dppf<0x141>(s[g]);
        }

        // ---- softmax over 32 candidates (4 per lane x 8 k_loc groups)
        float m = fmaxf(fmaxf(s[0], s[1]), fmaxf(s[2], s[3]));
        m = fmaxf(m, dppf<0x128>(m));        // xor8 (row_ror:8)
        m = fmaxf(m, __shfl_xor(m, 16));
        m = fmaxf(m, __shfl_xor(m, 32));
        float e0 = __expf(s[0] - m), e1 = __expf(s[1] - m);
        float e2 = __expf(s[2] - m), e3 = __expf(s[3] - m);
        float l = (e0 + e1) + (e2 + e3);
        l += dppf<0x128>(l);
        l += __shfl_xor(l, 16);
        l += __shfl_xor(l, 32);
        const float inv = 1.0f / l;
        const float a[4] = {e0 * inv, e1 * inv, e2 * inv, e3 * inv};

        // ---- phase 2: values (same lane layout; a,idx already in-register)
        float acc[8] = {0, 0, 0, 0, 0, 0, 0, 0};
#pragma unroll
        for (int g = 0; g < 4; ++g) {
            const float4 vraw =
                *(const float4*)(Rtb + ((size_t)idxg[g] << 6) + c_oct * 8);
            const __half2* v2 = (const __half2*)&vraw;
            const float ag = a[g];
#pragma unroll
            for (int u = 0; u < 4; ++u) {
                const float2 vf = __half22float2(v2[u]);
                acc[2 * u]     = fmaf(ag, vf.x, acc[2 * u]);
                acc[2 * u + 1] = fmaf(ag, vf.y, acc[2 * u + 1]);
            }
        }

        // ---- reduce acc[8] over k_loc (xor 8,16,32) with payload halving
        float r4[4];
#pragma unroll
        for (int i = 0; i < 4; ++i) {           // xor8 stage via DPP ror8
            const float send = hi8 ? acc[i] : acc[4 + i];
            const float recv = dppf<0x128>(send);
            r4[i] = (hi8 ? acc[4 + i] : acc[i]) + recv;
        }
        float r2[2];
#pragma unroll
        for (int i = 0; i < 2; ++i) {           // xor16 stage
            const float send = hi16 ? r4[i] : r4[2 + i];
            const float recv = __shfl_xor(send, 16);
            r2[i] = (hi16 ? r4[2 + i] : r4[i]) + recv;
        }
        {                                        // xor32 stage
            const float send = hi32 ? r2[0] : r2[1];
            const float recv = __shfl_xor(send, 32);
            const float r1   = (hi32 ? r2[1] : r2[0]) + recv;
            const int c = c_oct * 8 + (hi8 ? 4 : 0) + (hi16 ? 2 : 0) + (hi32 ? 1 : 0);
            ot[j][c] = r1;  // c distinct per lane; 2-way banks (free)
        }
    }
    __syncthreads();

    // ---- store: ot[j][c] -> Out[b][c][n0+j] (coalesced 256B along n)
    {
        const int j = tid & 63, c0 = tid >> 6;
        float* od = Out + (size_t)b * C * N + n0 + j;
#pragma unroll
        for (int r = 0; r < 8; ++r) {
            int c = c0 + r * 8;
            od[(size_t)c * N] = ot[j][c];
        }
    }
}

// ---------------------------------------------------------------------------
extern "C" void kernel_launch(void* const* d_in, const int* in_sizes, int n_in,
                              void* d_out, int out_size, void* d_ws, size_t ws_size,
                              hipStream_t stream) {
    const float* Q  = (const float*)d_in[0];
    const float* S  = (const float*)d_in[1];
    const float* R  = (const float*)d_in[2];
    const int*   Px = (const int*)d_in[3];
    const int*   Py = (const int*)d_in[4];
    float* Out = (float*)d_out;

    // workspace: St, Rt, Qt fp16 (4.19 MB each) + Idx uint16 (2.1 MB)
    __half* St = (__half*)d_ws;
    __half* Rt = St + (size_t)B * N * C;
    __half* Qt = Rt + (size_t)B * N * C;
    unsigned short* Idx = (unsigned short*)(Qt + (size_t)B * N * C);

    dim3 pgrid(N / 64, B, 4);
    fepam_prep<<<pgrid, 256, 0, stream>>>(Q, S, R, Px, Py, Qt, St, Rt, Idx);

    dim3 agrid(N / 64 * B);
    fepam_attn<<<agrid, 512, 0, stream>>>(Qt, Idx, St, Rt, Out);
}

// Round 6
// 139.933 us; speedup vs baseline: 1.1089x; 1.1089x over previous
//
#include <hip/hip_runtime.h>
#include <hip/hip_fp16.h>

// fePAM: per-pixel gather attention. Shapes fixed by setup_inputs().
constexpr int B = 2, C = 64, H = 128, W = 256, N = H * W, K = 32;

typedef _Float16 hf2 __attribute__((ext_vector_type(2)));

// DPP helper (VALU-pipe cross-lane)
template <int CTRL>
__device__ __forceinline__ float dppf(float x) {
    int i = __builtin_bit_cast(int, x);
    int r = __builtin_amdgcn_update_dpp(i, i, CTRL, 0xF, 0xF, false);
    return __builtin_bit_cast(float, r);
}
// 0xB1 quad_perm xor1 | 0x4E quad_perm xor2 | 0x141 row_half_mirror (xor4)
// 0x128 row_ror:8 == xor8 within a 16-lane row

// ---------------------------------------------------------------------------
// Prep: z=0/1/2 transpose+fp16 S,R,Q: [B][C][N] -> [B][N][C].
// z=3 (b==0 only): pack idx16[n][slot]=px*W+py, slot=(k&7)*4+(k>>3).
// grid = (N/64, B, 4), block = 256.
// ---------------------------------------------------------------------------
__global__ __launch_bounds__(256) void fepam_prep(
    const float* __restrict__ Q, const float* __restrict__ S,
    const float* __restrict__ R,
    const int* __restrict__ Px, const int* __restrict__ Py,
    __half* __restrict__ Qt, __half* __restrict__ St, __half* __restrict__ Rt,
    unsigned short* __restrict__ Idx) {
    const int n0 = blockIdx.x * 64;
    const int b  = blockIdx.y;
    const int z  = blockIdx.z;

    if (z == 3) {
        if (b) return;
#pragma unroll
        for (int t = 0; t < 8; ++t) {
            const int e  = threadIdx.x + 256 * t;   // 0..2047
            const int nl = e >> 5, k = e & 31;
            const int n  = n0 + nl;
            const int idx = Px[(size_t)n * K + k] * W + Py[(size_t)n * K + k];
            Idx[(size_t)n * K + (k & 7) * 4 + (k >> 3)] = (unsigned short)idx;
        }
        return;
    }

    __shared__ float tile[C][65];
    const float* src = (z == 0 ? S : (z == 1 ? R : Q)) + (size_t)b * C * N;
    __half2* d2 = (__half2*)((z == 0 ? St : (z == 1 ? Rt : Qt)) +
                             (size_t)b * N * C);
    {
        const int j = threadIdx.x & 63, c0 = threadIdx.x >> 6;
        const float* s = src + n0 + j;
#pragma unroll
        for (int r = 0; r < 16; ++r) {
            int c = c0 + r * 4;
            tile[c][j] = s[(size_t)c * N];  // coalesced 256B along n
        }
    }
    __syncthreads();
    {
        const int c2 = threadIdx.x & 31, j0 = threadIdx.x >> 5;
#pragma unroll
        for (int r = 0; r < 8; ++r) {
            int j = j0 + 8 * r;
            d2[(size_t)(n0 + j) * 32 + c2] =
                __floats2half2_rn(tile[2 * c2][j], tile[2 * c2 + 1][j]);
        }
    }
}

// ---------------------------------------------------------------------------
// Scores: touches ONLY St (4.19 MB per batch -> L2-resident per XCD).
// grid = (N/32 * B), block = 256 (4 waves; 1 wave = 8 pixels). No LDS.
// Lane layout: c_oct = lane&7 (16B chunk of 128B key), k_loc = lane>>3.
// Writes softmaxed attention weights fp16 to Attn[b][n][k_loc*4+g].
// ---------------------------------------------------------------------------
__global__ __launch_bounds__(256, 6) void fepam_scores(
    const __half* __restrict__ Qt, const unsigned short* __restrict__ Idx,
    const __half* __restrict__ St, __half* __restrict__ Attn) {
    const int tid  = threadIdx.x;
    const int lane = tid & 63;
    const int wave = tid >> 6;        // 0..3
    const int bx   = blockIdx.x;
    const int b    = bx & 1;          // XCD batch-parity swizzle
    const int n0   = (bx >> 1) * 32;

    const int c_oct = lane & 7;
    const int k_loc = lane >> 3;

    const __half* Qtb = Qt + (size_t)b * N * C;
    const __half* Stb = St + (size_t)b * N * C;
    __half* AttnB = Attn + (size_t)b * N * K;

#pragma unroll
    for (int p = 0; p < 8; ++p) {
        const int n = n0 + wave * 8 + p;

        const ushort4 iv = *(const ushort4*)(Idx + (size_t)n * K + k_loc * 4);
        const float4 qraw = *(const float4*)(Qtb + (size_t)n * C + c_oct * 8);
        const int idxg[4] = {iv.x, iv.y, iv.z, iv.w};

        float s[4];
#pragma unroll
        for (int g = 0; g < 4; ++g) {
            const float4 kraw =
                *(const float4*)(Stb + ((size_t)idxg[g] << 6) + c_oct * 8);
            const hf2* k2 = (const hf2*)&kraw;
            const hf2* q2 = (const hf2*)&qraw;
            float acc = 0.f;
#pragma unroll
            for (int u = 0; u < 4; ++u)
                acc = __builtin_amdgcn_fdot2(k2[u], q2[u], acc, false);
            s[g] = acc;
        }
#pragma unroll
        for (int g = 0; g < 4; ++g) {  // reduce over c_oct: pure DPP
            s[g] += dppf<0xB1>(s[g]);
            s[g] += dppf<0x4E>(s[g]);
            s[g] += dppf<0x141>(s[g]);
        }

        // softmax over 32 candidates (4 per lane x 8 k_loc groups)
        float m = fmaxf(fmaxf(s[0], s[1]), fmaxf(s[2], s[3]));
        m = fmaxf(m, dppf<0x128>(m));
        m = fmaxf(m, __shfl_xor(m, 16));
        m = fmaxf(m, __shfl_xor(m, 32));
        float e0 = __expf(s[0] - m), e1 = __expf(s[1] - m);
        float e2 = __expf(s[2] - m), e3 = __expf(s[3] - m);
        float l = (e0 + e1) + (e2 + e3);
        l += dppf<0x128>(l);
        l += __shfl_xor(l, 16);
        l += __shfl_xor(l, 32);
        const float inv = 1.0f / l;

        if (c_oct == 0) {  // 8 lanes x 8B = contiguous 64B per pixel
            ushort4 av;
            av.x = __half_as_ushort(__float2half_rn(e0 * inv));
            av.y = __half_as_ushort(__float2half_rn(e1 * inv));
            av.z = __half_as_ushort(__float2half_rn(e2 * inv));
            av.w = __half_as_ushort(__float2half_rn(e3 * inv));
            *(ushort4*)(AttnB + (size_t)n * K + k_loc * 4) = av;
        }
    }
}

// ---------------------------------------------------------------------------
// Values: touches ONLY Rt (4.19 MB per batch -> L2-resident per XCD).
// grid = (N/32 * B), block = 256 (4 waves; 1 wave = 8 pixels). LDS 8.4 KB.
// ---------------------------------------------------------------------------
__global__ __launch_bounds__(256, 6) void fepam_values(
    const unsigned short* __restrict__ Idx, const __half* __restrict__ Attn,
    const __half* __restrict__ Rt, float* __restrict__ Out) {
    __shared__ __align__(16) float ot[32][66];  // 8.4 KB

    const int tid  = threadIdx.x;
    const int lane = tid & 63;
    const int wave = tid >> 6;        // 0..3
    const int bx   = blockIdx.x;
    const int b    = bx & 1;
    const int n0   = (bx >> 1) * 32;

    const int c_oct = lane & 7;
    const int k_loc = lane >> 3;
    const bool hi8  = (lane & 8)  != 0;
    const bool hi16 = (lane & 16) != 0;
    const bool hi32 = (lane & 32) != 0;

    const __half* Rtb = Rt + (size_t)b * N * C;
    const __half* AttnB = Attn + (size_t)b * N * K;

#pragma unroll
    for (int p = 0; p < 8; ++p) {
        const int j = wave * 8 + p;
        const int n = n0 + j;

        const ushort4 iv = *(const ushort4*)(Idx + (size_t)n * K + k_loc * 4);
        const ushort4 av = *(const ushort4*)(AttnB + (size_t)n * K + k_loc * 4);
        const int idxg[4] = {iv.x, iv.y, iv.z, iv.w};
        const float a[4] = {__half2float(__ushort_as_half(av.x)),
                            __half2float(__ushort_as_half(av.y)),
                            __half2float(__ushort_as_half(av.z)),
                            __half2float(__ushort_as_half(av.w))};

        float acc[8] = {0, 0, 0, 0, 0, 0, 0, 0};
#pragma unroll
        for (int g = 0; g < 4; ++g) {
            const float4 vraw =
                *(const float4*)(Rtb + ((size_t)idxg[g] << 6) + c_oct * 8);
            const __half2* v2 = (const __half2*)&vraw;
#pragma unroll
            for (int u = 0; u < 4; ++u) {
                const float2 vf = __half22float2(v2[u]);
                acc[2 * u]     = fmaf(a[g], vf.x, acc[2 * u]);
                acc[2 * u + 1] = fmaf(a[g], vf.y, acc[2 * u + 1]);
            }
        }

        // reduce acc[8] over k_loc (xor 8,16,32) with payload halving
        float r4[4];
#pragma unroll
        for (int i = 0; i < 4; ++i) {
            const float send = hi8 ? acc[i] : acc[4 + i];
            const float recv = dppf<0x128>(send);
            r4[i] = (hi8 ? acc[4 + i] : acc[i]) + recv;
        }
        float r2[2];
#pragma unroll
        for (int i = 0; i < 2; ++i) {
            const float send = hi16 ? r4[i] : r4[2 + i];
            const float recv = __shfl_xor(send, 16);
            r2[i] = (hi16 ? r4[2 + i] : r4[i]) + recv;
        }
        {
            const float send = hi32 ? r2[0] : r2[1];
            const float recv = __shfl_xor(send, 32);
            const float r1   = (hi32 ? r2[1] : r2[0]) + recv;
            const int c = c_oct * 8 + (hi8 ? 4 : 0) + (hi16 ? 2 : 0) + (hi32 ? 1 : 0);
            ot[j][c] = r1;
        }
    }
    __syncthreads();

    // store: ot[j][c] -> Out[b][c][n0+j] (two 128B segments per instr)
    {
        const int j = tid & 31, c0 = tid >> 5;
        float* od = Out + (size_t)b * C * N + n0 + j;
#pragma unroll
        for (int r = 0; r < 8; ++r) {
            int c = c0 + r * 8;
            od[(size_t)c * N] = ot[j][c];
        }
    }
}

// ---------------------------------------------------------------------------
extern "C" void kernel_launch(void* const* d_in, const int* in_sizes, int n_in,
                              void* d_out, int out_size, void* d_ws, size_t ws_size,
                              hipStream_t stream) {
    const float* Q  = (const float*)d_in[0];
    const float* S  = (const float*)d_in[1];
    const float* R  = (const float*)d_in[2];
    const int*   Px = (const int*)d_in[3];
    const int*   Py = (const int*)d_in[4];
    float* Out = (float*)d_out;

    // ws: St, Rt, Qt (8.39 MB each) + Idx (2.1 MB) + Attn (4.19 MB) = 31.5 MB
    __half* St = (__half*)d_ws;
    __half* Rt = St + (size_t)B * N * C;
    __half* Qt = Rt + (size_t)B * N * C;
    unsigned short* Idx = (unsigned short*)(Qt + (size_t)B * N * C);
    __half* Attn = (__half*)(Idx + (size_t)N * K);

    dim3 pgrid(N / 64, B, 4);
    fepam_prep<<<pgrid, 256, 0, stream>>>(Q, S, R, Px, Py, Qt, St, Rt, Idx);

    dim3 ggrid(N / 32 * B);
    fepam_scores<<<ggrid, 256, 0, stream>>>(Qt, Idx, St, Attn);
    fepam_values<<<ggrid, 256, 0, stream>>>(Idx, Attn, Rt, Out);
}

// Round 8
// 137.249 us; speedup vs baseline: 1.1306x; 1.0196x over previous
//
#include <hip/hip_runtime.h>
#include <hip/hip_fp16.h>

// fePAM: per-pixel gather attention. Shapes fixed by setup_inputs().
constexpr int B = 2, C = 64, H = 128, W = 256, N = H * W, K = 32;

typedef _Float16 hf2 __attribute__((ext_vector_type(2)));

// DPP helper (VALU-pipe cross-lane)
template <int CTRL>
__device__ __forceinline__ float dppf(float x) {
    int i = __builtin_bit_cast(int, x);
    int r = __builtin_amdgcn_update_dpp(i, i, CTRL, 0xF, 0xF, false);
    return __builtin_bit_cast(float, r);
}
// 0xB1 quad_perm xor1 | 0x4E quad_perm xor2 | 0x141 row_half_mirror (xor4)
// 0x128 row_ror:8 == xor8 within a 16-lane row

__device__ __forceinline__ unsigned sel4(const uint4& v, int g) {
    return g == 0 ? v.x : g == 1 ? v.y : g == 2 ? v.z : v.w;
}
__device__ __forceinline__ unsigned sel4(const ushort4& v, int g) {
    return g == 0 ? v.x : g == 1 ? v.y : g == 2 ? v.z : v.w;
}

// ---------------------------------------------------------------------------
// Prep: z=0/1/2 transpose+fp16 S,R,Q: [B][C][N] -> [B][N][C].
// z=3 (b==0 only): pack idx16[n][slot]=px*W+py, slot=(k&7)*4+(k>>3).
// grid = (N/64, B, 4), block = 256.
// ---------------------------------------------------------------------------
__global__ __launch_bounds__(256) void fepam_prep(
    const float* __restrict__ Q, const float* __restrict__ S,
    const float* __restrict__ R,
    const int* __restrict__ Px, const int* __restrict__ Py,
    __half* __restrict__ Qt, __half* __restrict__ St, __half* __restrict__ Rt,
    unsigned short* __restrict__ Idx) {
    const int n0 = blockIdx.x * 64;
    const int b  = blockIdx.y;
    const int z  = blockIdx.z;

    if (z == 3) {
        if (b) return;
#pragma unroll
        for (int t = 0; t < 8; ++t) {
            const int e  = threadIdx.x + 256 * t;   // 0..2047
            const int nl = e >> 5, k = e & 31;
            const int n  = n0 + nl;
            const int idx = Px[(size_t)n * K + k] * W + Py[(size_t)n * K + k];
            Idx[(size_t)n * K + (k & 7) * 4 + (k >> 3)] = (unsigned short)idx;
        }
        return;
    }

    __shared__ float tile[C][65];
    const float* src = (z == 0 ? S : (z == 1 ? R : Q)) + (size_t)b * C * N;
    __half2* d2 = (__half2*)((z == 0 ? St : (z == 1 ? Rt : Qt)) +
                             (size_t)b * N * C);
    {
        const int j = threadIdx.x & 63, c0 = threadIdx.x >> 6;
        const float* s = src + n0 + j;
#pragma unroll
        for (int r = 0; r < 16; ++r) {
            int c = c0 + r * 4;
            tile[c][j] = s[(size_t)c * N];  // coalesced 256B along n
        }
    }
    __syncthreads();
    {
        const int c2 = threadIdx.x & 31, j0 = threadIdx.x >> 5;
#pragma unroll
        for (int r = 0; r < 8; ++r) {
            int j = j0 + 8 * r;
            d2[(size_t)(n0 + j) * 32 + c2] =
                __floats2half2_rn(tile[2 * c2][j], tile[2 * c2 + 1][j]);
        }
    }
}

// ---------------------------------------------------------------------------
// Scores: touches ONLY St (4.19 MB/batch -> L2-resident per XCD).
// grid = (N/32 * B), block = 256 (4 waves; 1 wave = 8 pixels). No LDS.
// Software-pipelined: iv/q loaded 2 pixels ahead, keys 1 pixel ahead.
// Writes packed (idx<<16 | fp16 attn) to AI[b][n][k_loc*4+g].
// ---------------------------------------------------------------------------
__global__ __launch_bounds__(256, 6) void fepam_scores(
    const __half* __restrict__ Qt, const unsigned short* __restrict__ Idx,
    const __half* __restrict__ St, unsigned* __restrict__ AI) {
    const int tid  = threadIdx.x;
    const int lane = tid & 63;
    const int wave = tid >> 6;        // 0..3
    const int bx   = blockIdx.x;
    const int b    = bx & 1;          // XCD batch-parity swizzle
    const int n0   = (bx >> 1) * 32 + wave * 8;

    const int c_oct = lane & 7;
    const int k_loc = lane >> 3;

    const __half* Qtb = Qt + (size_t)b * N * C;
    const __half* Stb = St + (size_t)b * N * C;
    unsigned* AIb = AI + (size_t)b * N * K;

    auto ldi = [&](int p) {
        return *(const ushort4*)(Idx + (size_t)(n0 + p) * K + k_loc * 4);
    };
    auto ldq = [&](int p) {
        return *(const float4*)(Qtb + (size_t)(n0 + p) * C + c_oct * 8);
    };
    auto ldk = [&](const ushort4& iv, int g) {
        return *(const float4*)(Stb + ((size_t)sel4(iv, g) << 6) + c_oct * 8);
    };

    ushort4 iv_c = ldi(0), iv_n = ldi(1);
    float4  q_c  = ldq(0), q_n  = ldq(1);
    float4  k_c[4];
#pragma unroll
    for (int g = 0; g < 4; ++g) k_c[g] = ldk(iv_c, g);

#pragma unroll
    for (int p = 0; p < 8; ++p) {
        // prefetch: keys for p+1, iv/q for p+2
        float4 k_n[4];
        if (p < 7) {
#pragma unroll
            for (int g = 0; g < 4; ++g) k_n[g] = ldk(iv_n, g);
        }
        ushort4 iv_2;
        float4  q_2;
        if (p < 6) { iv_2 = ldi(p + 2); q_2 = ldq(p + 2); }

        // ---- compute pixel p
        float s[4];
#pragma unroll
        for (int g = 0; g < 4; ++g) {
            const hf2* k2 = (const hf2*)&k_c[g];
            const hf2* q2 = (const hf2*)&q_c;
            float acc = 0.f;
#pragma unroll
            for (int u = 0; u < 4; ++u)
                acc = __builtin_amdgcn_fdot2(k2[u], q2[u], acc, false);
            s[g] = acc;
        }
#pragma unroll
        for (int g = 0; g < 4; ++g) {  // reduce over c_oct: pure DPP
            s[g] += dppf<0xB1>(s[g]);
            s[g] += dppf<0x4E>(s[g]);
            s[g] += dppf<0x141>(s[g]);
        }
        float m = fmaxf(fmaxf(s[0], s[1]), fmaxf(s[2], s[3]));
        m = fmaxf(m, dppf<0x128>(m));
        m = fmaxf(m, __shfl_xor(m, 16));
        m = fmaxf(m, __shfl_xor(m, 32));
        float e0 = __expf(s[0] - m), e1 = __expf(s[1] - m);
        float e2 = __expf(s[2] - m), e3 = __expf(s[3] - m);
        float l = (e0 + e1) + (e2 + e3);
        l += dppf<0x128>(l);
        l += __shfl_xor(l, 16);
        l += __shfl_xor(l, 32);
        const float inv = 1.0f / l;

        if (c_oct == 0) {  // 8 lanes x 16B = contiguous 128B per pixel
            uint4 wv;
            wv.x = ((unsigned)iv_c.x << 16) |
                   __half_as_ushort(__float2half_rn(e0 * inv));
            wv.y = ((unsigned)iv_c.y << 16) |
                   __half_as_ushort(__float2half_rn(e1 * inv));
            wv.z = ((unsigned)iv_c.z << 16) |
                   __half_as_ushort(__float2half_rn(e2 * inv));
            wv.w = ((unsigned)iv_c.w << 16) |
                   __half_as_ushort(__float2half_rn(e3 * inv));
            *(uint4*)(AIb + (size_t)(n0 + p) * K + k_loc * 4) = wv;
        }

        // ---- shift pipeline
#pragma unroll
        for (int g = 0; g < 4; ++g) k_c[g] = k_n[g];
        iv_c = iv_n; q_c = q_n;
        iv_n = iv_2; q_n = q_2;
    }
}

// ---------------------------------------------------------------------------
// Values: touches ONLY Rt (4.19 MB/batch -> L2-resident per XCD).
// grid = (N/32 * B), block = 256 (4 waves; 1 wave = 8 pixels). LDS 8.4 KB.
// Software-pipelined like fepam_scores; reads packed (idx|attn) words.
// ---------------------------------------------------------------------------
__global__ __launch_bounds__(256, 6) void fepam_values(
    const unsigned* __restrict__ AI, const __half* __restrict__ Rt,
    float* __restrict__ Out) {
    __shared__ __align__(16) float ot[32][66];  // 8.4 KB

    const int tid  = threadIdx.x;
    const int lane = tid & 63;
    const int wave = tid >> 6;        // 0..3
    const int bx   = blockIdx.x;
    const int b    = bx & 1;
    const int n0t  = (bx >> 1) * 32;
    const int n0   = n0t + wave * 8;

    const int c_oct = lane & 7;
    const int k_loc = lane >> 3;
    const bool hi8  = (lane & 8)  != 0;
    const bool hi16 = (lane & 16) != 0;
    const bool hi32 = (lane & 32) != 0;

    const __half* Rtb = Rt + (size_t)b * N * C;
    const unsigned* AIb = AI + (size_t)b * N * K;

    auto ldw = [&](int p) {
        return *(const uint4*)(AIb + (size_t)(n0 + p) * K + k_loc * 4);
    };
    auto ldv = [&](const uint4& wv, int g) {
        return *(const float4*)(Rtb + ((size_t)(sel4(wv, g) >> 16) << 6) +
                                c_oct * 8);
    };

    uint4  w_c = ldw(0), w_n = ldw(1);
    float4 v_c[4];
#pragma unroll
    for (int g = 0; g < 4; ++g) v_c[g] = ldv(w_c, g);

#pragma unroll
    for (int p = 0; p < 8; ++p) {
        float4 v_n[4];
        if (p < 7) {
#pragma unroll
            for (int g = 0; g < 4; ++g) v_n[g] = ldv(w_n, g);
        }
        uint4 w_2;
        if (p < 6) w_2 = ldw(p + 2);

        // ---- compute pixel p
        const float a[4] = {
            __half2float(__ushort_as_half((unsigned short)(w_c.x & 0xffffu))),
            __half2float(__ushort_as_half((unsigned short)(w_c.y & 0xffffu))),
            __half2float(__ushort_as_half((unsigned short)(w_c.z & 0xffffu))),
            __half2float(__ushort_as_half((unsigned short)(w_c.w & 0xffffu)))};
        float acc[8] = {0, 0, 0, 0, 0, 0, 0, 0};
#pragma unroll
        for (int g = 0; g < 4; ++g) {
            const __half2* v2 = (const __half2*)&v_c[g];
#pragma unroll
            for (int u = 0; u < 4; ++u) {
                const float2 vf = __half22float2(v2[u]);
                acc[2 * u]     = fmaf(a[g], vf.x, acc[2 * u]);
                acc[2 * u + 1] = fmaf(a[g], vf.y, acc[2 * u + 1]);
            }
        }

        // reduce acc[8] over k_loc (xor 8,16,32) with payload halving
        float r4[4];
#pragma unroll
        for (int i = 0; i < 4; ++i) {
            const float send = hi8 ? acc[i] : acc[4 + i];
            const float recv = dppf<0x128>(send);
            r4[i] = (hi8 ? acc[4 + i] : acc[i]) + recv;
        }
        float r2[2];
#pragma unroll
        for (int i = 0; i < 2; ++i) {
            const float send = hi16 ? r4[i] : r4[2 + i];
            const float recv = __shfl_xor(send, 16);
            r2[i] = (hi16 ? r4[2 + i] : r4[i]) + recv;
        }
        {
            const float send = hi32 ? r2[0] : r2[1];
            const float recv = __shfl_xor(send, 32);
            const float r1   = (hi32 ? r2[1] : r2[0]) + recv;
            const int c = c_oct * 8 + (hi8 ? 4 : 0) + (hi16 ? 2 : 0) + (hi32 ? 1 : 0);
            ot[wave * 8 + p][c] = r1;
        }

        // ---- shift pipeline
#pragma unroll
        for (int g = 0; g < 4; ++g) v_c[g] = v_n[g];
        w_c = w_n;
        w_n = w_2;
    }
    __syncthreads();

    // store: ot[j][c] -> Out[b][c][n0t+j] (two 128B segments per instr)
    {
        const int j = tid & 31, c0 = tid >> 5;
        float* od = Out + (size_t)b * C * N + n0t + j;
#pragma unroll
        for (int r = 0; r < 8; ++r) {
            int c = c0 + r * 8;
            od[(size_t)c * N] = ot[j][c];
        }
    }
}

// ---------------------------------------------------------------------------
extern "C" void kernel_launch(void* const* d_in, const int* in_sizes, int n_in,
                              void* d_out, int out_size, void* d_ws, size_t ws_size,
                              hipStream_t stream) {
    const float* Q  = (const float*)d_in[0];
    const float* S  = (const float*)d_in[1];
    const float* R  = (const float*)d_in[2];
    const int*   Px = (const int*)d_in[3];
    const int*   Py = (const int*)d_in[4];
    float* Out = (float*)d_out;

    // ws: St, Rt, Qt (8.39 MB each) + Idx (2.1 MB) + AI packed (8.39 MB)
    __half* St = (__half*)d_ws;
    __half* Rt = St + (size_t)B * N * C;
    __half* Qt = Rt + (size_t)B * N * C;
    unsigned short* Idx = (unsigned short*)(Qt + (size_t)B * N * C);
    unsigned* AI = (unsigned*)(Idx + (size_t)N * K);

    dim3 pgrid(N / 64, B, 4);
    fepam_prep<<<pgrid, 256, 0, stream>>>(Q, S, R, Px, Py, Qt, St, Rt, Idx);

    dim3 ggrid(N / 32 * B);
    fepam_scores<<<ggrid, 256, 0, stream>>>(Qt, Idx, St, AI);
    fepam_values<<<ggrid, 256, 0, stream>>>(AI, Rt, Out);
}